// Round 5
// baseline (807.892 us; speedup 1.0000x reference)
//
#include <hip/hip_runtime.h>
#include <hip/hip_bf16.h>
#include <hip/hip_fp16.h>

// GIN via linearity: agg(x)@W == agg(x@W). Per layer: z = X@W (fp32 compute,
// fp16 store), then h = relu(z + gather_sum(z) + b) via on-device CSR.
// CSR: coarse bucket sort (dst>>8) with LDS-local finalize (no global scan,
// no global cursors). GEMM: 4x4 register blocking, b128 LDS reads.

#define N_FEAT 64
#define CHUNK 2048
#define CAP 6144   // max edges per coarse bucket held in LDS (mean 4096)

// ---- GEMM: 64 rows/block, 256 threads, 4x4 register blocking ----
template <typename TIN>
__global__ void gemm64(const TIN* __restrict__ X, const float* __restrict__ W,
                       __half* __restrict__ Z, int nrows) {
    __shared__ float sXT[64][68];   // [k][r], padded
    __shared__ float sW[64][64];    // [k][c]
    int t = threadIdx.x;
    int base = blockIdx.x * 64;
    int nvalid = min(64, nrows - base);
    for (int idx = t; idx < 4096; idx += 256) sW[idx >> 6][idx & 63] = W[idx];
    for (int idx = t; idx < 4096; idx += 256) {
        int r = idx >> 6, c = idx & 63;
        float v = (r < nvalid) ? (float)X[(size_t)(base + r) * 64 + c] : 0.f;
        sXT[c][r] = v;
    }
    __syncthreads();
    int cg = (t & 15) * 4;          // col base
    int rg = (t >> 4) * 4;          // row base
    float acc[4][4] = {};
#pragma unroll
    for (int k = 0; k < 64; ++k) {
        float4 a = *(const float4*)&sXT[k][rg];
        float4 w = *(const float4*)&sW[k][cg];
        acc[0][0] += a.x * w.x; acc[0][1] += a.x * w.y; acc[0][2] += a.x * w.z; acc[0][3] += a.x * w.w;
        acc[1][0] += a.y * w.x; acc[1][1] += a.y * w.y; acc[1][2] += a.y * w.z; acc[1][3] += a.y * w.w;
        acc[2][0] += a.z * w.x; acc[2][1] += a.z * w.y; acc[2][2] += a.z * w.z; acc[2][3] += a.z * w.w;
        acc[3][0] += a.w * w.x; acc[3][1] += a.w * w.y; acc[3][2] += a.w * w.z; acc[3][3] += a.w * w.w;
    }
#pragma unroll
    for (int i = 0; i < 4; ++i) {
        int row = base + rg + i;
        if (row < nrows) {
            __half2 p0 = __floats2half2_rn(acc[i][0], acc[i][1]);
            __half2 p1 = __floats2half2_rn(acc[i][2], acc[i][3]);
            float2 pack;
            *(__half2*)&pack.x = p0;
            *(__half2*)&pack.y = p1;
            *(float2*)&Z[(size_t)row * 64 + cg] = pack;
        }
    }
}

// ---- CSR build ----
// coarse histogram: edges per 256-node bucket
__global__ void coarse_hist(const int* __restrict__ dst, int* __restrict__ bcnt, int E) {
    __shared__ int h[256];
    int t = threadIdx.x;
    h[t] = 0;
    __syncthreads();
    for (int i = blockIdx.x * blockDim.x + t; i < E; i += gridDim.x * blockDim.x)
        atomicAdd(&h[dst[i] >> 8], 1);
    __syncthreads();
    if (h[t] > 0) atomicAdd(&bcnt[t], h[t]);
}

// scan bucket counts -> bucket offsets + pass-A cursors; rowptr[N]=E
__global__ void bucket_offsets(const int* __restrict__ bcnt, int* __restrict__ boff,
                               int* __restrict__ ccur, int nb, int E,
                               int* __restrict__ rowptr, int N) {
    __shared__ int s[256];
    int t = threadIdx.x;
    int v = (t < nb) ? bcnt[t] : 0;
    s[t] = v;
    __syncthreads();
    for (int off = 1; off < 256; off <<= 1) {
        int u = (t >= off) ? s[t - off] : 0;
        __syncthreads();
        s[t] += u;
        __syncthreads();
    }
    int excl = s[t] - v;
    if (t < nb) { boff[t] = excl; ccur[t] = excl; }
    if (t == 0) { boff[nb] = E; rowptr[N] = E; }
}

// pass A: coarse-bucket (src,dst) into staging, LDS-staged chunks
__global__ void bucket_scatter(const int* __restrict__ src, const int* __restrict__ dst,
                               int* __restrict__ ccur, int2* __restrict__ staging, int E) {
    __shared__ int esrc[CHUNK];
    __shared__ int edst[CHUNK];
    __shared__ int hist[256];
    __shared__ int base[256];
    int t = threadIdx.x;
    int begin = blockIdx.x * CHUNK;
    int cnt = min(CHUNK, E - begin);
    hist[t] = 0;
    __syncthreads();
    for (int i = t; i < cnt; i += 256) {
        int d = dst[begin + i];
        esrc[i] = src[begin + i];
        edst[i] = d;
        atomicAdd(&hist[d >> 8], 1);
    }
    __syncthreads();
    int h = hist[t];
    if (h > 0) base[t] = atomicAdd(&ccur[t], h);
    hist[t] = 0;
    __syncthreads();
    for (int i = t; i < cnt; i += 256) {
        int d = edst[i];
        int b = d >> 8;
        int p = base[b] + atomicAdd(&hist[b], 1);
        staging[p] = make_int2(esrc[i], d);
    }
}

// pass B: one block per bucket; per-node hist+scan+scatter fully in LDS
__global__ void bucket_finalize(const int2* __restrict__ staging, const int* __restrict__ boff,
                                int* __restrict__ rowptr, int* __restrict__ col, int N) {
    __shared__ int2 edges[CAP];
    __shared__ int hist[256];
    __shared__ int scan[256];
    __shared__ int cur[256];
    int b = blockIdx.x, t = threadIdx.x;
    int lo = boff[b], hi = boff[b + 1];
    int cnt = hi - lo;
    hist[t] = 0;
    __syncthreads();
    for (int i = t; i < cnt; i += 256) {
        int2 e = staging[lo + i];
        if (i < CAP) edges[i] = e;
        atomicAdd(&hist[e.y & 255], 1);
    }
    __syncthreads();
    int v = hist[t];
    scan[t] = v;
    __syncthreads();
    for (int off = 1; off < 256; off <<= 1) {
        int u = (t >= off) ? scan[t - off] : 0;
        __syncthreads();
        scan[t] += u;
        __syncthreads();
    }
    int excl = scan[t] - v;
    cur[t] = excl;
    int node = b * 256 + t;
    if (node < N) rowptr[node] = lo + excl;
    __syncthreads();
    for (int i = t; i < cnt; i += 256) {
        int2 e = (i < CAP) ? edges[i] : staging[lo + i];
        int pos = lo + atomicAdd(&cur[e.y & 255], 1);
        col[pos] = e.x;
    }
}

// ---- gather + bias + relu; 1 wave/node; 16 rows in flight ----
__global__ void gather_relu(const __half* __restrict__ Z, const int* __restrict__ rowptr,
                            const int* __restrict__ col, const float* __restrict__ bias,
                            __half* __restrict__ H, int n) {
    int node = (int)((blockIdx.x * blockDim.x + threadIdx.x) >> 6);
    if (node >= n) return;
    int lane = threadIdx.x & 63;
    int g = lane >> 4, l = lane & 15;
    int lo = rowptr[node], hi = rowptr[node + 1];
    const float2* Z2 = reinterpret_cast<const float2*>(Z);
    float ax = 0.f, ay = 0.f, az = 0.f, aw = 0.f;
    int j = lo + g;
    while (j + 12 < hi) {
        int s0 = col[j], s1 = col[j + 4], s2 = col[j + 8], s3 = col[j + 12];
        float2 r0 = Z2[(size_t)s0 * 16 + l];
        float2 r1 = Z2[(size_t)s1 * 16 + l];
        float2 r2 = Z2[(size_t)s2 * 16 + l];
        float2 r3 = Z2[(size_t)s3 * 16 + l];
        float2 f;
        f = __half22float2(*(__half2*)&r0.x); ax += f.x; ay += f.y;
        f = __half22float2(*(__half2*)&r0.y); az += f.x; aw += f.y;
        f = __half22float2(*(__half2*)&r1.x); ax += f.x; ay += f.y;
        f = __half22float2(*(__half2*)&r1.y); az += f.x; aw += f.y;
        f = __half22float2(*(__half2*)&r2.x); ax += f.x; ay += f.y;
        f = __half22float2(*(__half2*)&r2.y); az += f.x; aw += f.y;
        f = __half22float2(*(__half2*)&r3.x); ax += f.x; ay += f.y;
        f = __half22float2(*(__half2*)&r3.y); az += f.x; aw += f.y;
        j += 16;
    }
    for (; j < hi; j += 4) {
        float2 r = Z2[(size_t)col[j] * 16 + l];
        float2 f0 = __half22float2(*(__half2*)&r.x);
        float2 f1 = __half22float2(*(__half2*)&r.y);
        ax += f0.x; ay += f0.y; az += f1.x; aw += f1.y;
    }
    ax += __shfl_xor(ax, 16); ay += __shfl_xor(ay, 16);
    az += __shfl_xor(az, 16); aw += __shfl_xor(aw, 16);
    ax += __shfl_xor(ax, 32); ay += __shfl_xor(ay, 32);
    az += __shfl_xor(az, 32); aw += __shfl_xor(aw, 32);
    if (g == 0) {
        float2 sr = Z2[(size_t)node * 16 + l];
        float2 fs0 = __half22float2(*(__half2*)&sr.x);
        float2 fs1 = __half22float2(*(__half2*)&sr.y);
        float4 b = reinterpret_cast<const float4*>(bias)[l];
        __half2 o0 = __floats2half2_rn(fmaxf(fs0.x + ax + b.x, 0.f),
                                       fmaxf(fs0.y + ay + b.y, 0.f));
        __half2 o1 = __floats2half2_rn(fmaxf(fs1.x + az + b.z, 0.f),
                                       fmaxf(fs1.y + aw + b.w, 0.f));
        float2 outv;
        *(__half2*)&outv.x = o0;
        *(__half2*)&outv.y = o1;
        reinterpret_cast<float2*>(H)[(size_t)node * 16 + l] = outv;
    }
}

// ---- fused mean-pool + linear head; 256 threads/graph ----
__global__ void pool_head(const __half* __restrict__ H, const int* __restrict__ batch,
                          const float* __restrict__ W3, const float* __restrict__ b3,
                          float* __restrict__ out, int n, int ncls) {
    int gidx = blockIdx.x;
    __shared__ int bounds[2];
    __shared__ float sred[4 * 64];
    __shared__ float row[64];
    int t = threadIdx.x;                 // 0..255
    int w = t >> 6;
    int lane = t & 63;
    int g = lane >> 4, l = lane & 15;
    if (t < 2) {
        int target = gidx + t;
        int lo = 0, hi = n;
        while (lo < hi) { int m = (lo + hi) >> 1; if (batch[m] < target) lo = m + 1; else hi = m; }
        bounds[t] = lo;
    }
    __syncthreads();
    int lo = bounds[0], hi = bounds[1];
    const float2* H2 = reinterpret_cast<const float2*>(H);
    float ax = 0.f, ay = 0.f, az = 0.f, aw = 0.f;
    for (int i = lo + (w * 4 + g); i < hi; i += 16) {
        float2 raw = H2[(size_t)i * 16 + l];
        float2 f0 = __half22float2(*(__half2*)&raw.x);
        float2 f1 = __half22float2(*(__half2*)&raw.y);
        ax += f0.x; ay += f0.y; az += f1.x; aw += f1.y;
    }
    ax += __shfl_xor(ax, 16); ay += __shfl_xor(ay, 16);
    az += __shfl_xor(az, 16); aw += __shfl_xor(aw, 16);
    ax += __shfl_xor(ax, 32); ay += __shfl_xor(ay, 32);
    az += __shfl_xor(az, 32); aw += __shfl_xor(aw, 32);
    if (g == 0) {
        sred[w * 64 + l * 4 + 0] = ax;
        sred[w * 64 + l * 4 + 1] = ay;
        sred[w * 64 + l * 4 + 2] = az;
        sred[w * 64 + l * 4 + 3] = aw;
    }
    __syncthreads();
    if (w == 0) {
        float s = sred[lane] + sred[64 + lane] + sred[128 + lane] + sred[192 + lane];
        row[lane] = s / fmaxf((float)(hi - lo), 1.0f);
    }
    __syncthreads();
    if (t < ncls) {
        float o = b3[t];
#pragma unroll
        for (int k = 0; k < 64; ++k) o += row[k] * W3[k * ncls + t];
        out[gidx * ncls + t] = o;
    }
}

extern "C" void kernel_launch(void* const* d_in, const int* in_sizes, int n_in,
                              void* d_out, int out_size, void* d_ws, size_t ws_size,
                              hipStream_t stream) {
    const float* x     = (const float*)d_in[0];
    const int*   ei    = (const int*)d_in[1];   // [2, E]
    const int*   batch = (const int*)d_in[2];
    const float* W1    = (const float*)d_in[3];
    const float* b1    = (const float*)d_in[4];
    const float* W2    = (const float*)d_in[5];
    const float* b2    = (const float*)d_in[6];
    const float* W3    = (const float*)d_in[7];
    const float* b3    = (const float*)d_in[8];
    float* out = (float*)d_out;

    const int N = in_sizes[0] / N_FEAT;       // 50000
    const int E = in_sizes[1] / 2;            // 800000
    const int NCLS = 10;
    const int G = out_size / NCLS;            // 500
    const int* src = ei;
    const int* dst = ei + E;

    // workspace layout
    int2*   staging = (int2*)d_ws;                        // E pairs
    __half* zbuf    = (__half*)(staging + E);             // N*64 fp16
    __half* hbuf    = zbuf + (size_t)N * 64;              // N*64 fp16
    int*    rowptr  = (int*)(hbuf + (size_t)N * 64);      // N+1
    int*    bcnt    = rowptr + (N + 1);                   // 256
    int*    boff    = bcnt + 256;                         // 257
    int*    ccur    = boff + 257;                         // 256
    int*    col     = ccur + 256;                         // E

    const int gemmGrid = (N + 63) / 64;
    const int gatherGrid = (N + 3) / 4;
    const int nb = (N + 255) / 256;           // 196 buckets
    const int scatGrid = (E + CHUNK - 1) / CHUNK;

    // ---- build CSR ----
    hipMemsetAsync(bcnt, 0, 256 * sizeof(int), stream);
    coarse_hist<<<400, 256, 0, stream>>>(dst, bcnt, E);
    bucket_offsets<<<1, 256, 0, stream>>>(bcnt, boff, ccur, nb, E, rowptr, N);
    bucket_scatter<<<scatGrid, 256, 0, stream>>>(src, dst, ccur, staging, E);
    bucket_finalize<<<nb, 256, 0, stream>>>(staging, boff, rowptr, col, N);

    // ---- layer 1 ----
    gemm64<float><<<gemmGrid, 256, 0, stream>>>(x, W1, zbuf, N);
    gather_relu<<<gatherGrid, 256, 0, stream>>>(zbuf, rowptr, col, b1, hbuf, N);

    // ---- layer 2 ----
    gemm64<__half><<<gemmGrid, 256, 0, stream>>>(hbuf, W2, zbuf, N);
    gather_relu<<<gatherGrid, 256, 0, stream>>>(zbuf, rowptr, col, b2, hbuf, N);

    // ---- pool + head ----
    pool_head<<<G, 256, 0, stream>>>(hbuf, batch, W3, b3, out, N, NCLS);
}

// Round 6
// 259.944 us; speedup vs baseline: 3.1079x; 3.1079x over previous
//
#include <hip/hip_runtime.h>
#include <hip/hip_bf16.h>
#include <hip/hip_fp16.h>

// GIN via linearity: agg(x)@W == agg(x@W). Per layer: z = X@W (fp32 compute,
// fp16 store), then h = relu(z + gather_sum(z) + b) via on-device CSR.
// CSR: coarse bucket sort (dst>>8) with LDS-local finalize (no global scan,
// no global cursors).
// NOTE: round-5's 4x4 register-blocked gemm64 regressed 10x (800 MB of
// hidden HBM traffic, scratch-like signature) — reverted to the round-4
// gemm64 structure which measured <45 us.

#define N_FEAT 64
#define CHUNK 2048
#define CAP 6144   // max edges per coarse bucket held in LDS (mean 4096)

// ---- GEMM: 64 rows per block, 256 threads, W + X tile in LDS; fp16 out ----
// thread = (row-group rg, col c); inner reads are wave-uniform sX[r][k]
// (broadcast) + conflict-free sW[k*64+c].
template <typename TIN>
__global__ void gemm64(const TIN* __restrict__ X, const float* __restrict__ W,
                       __half* __restrict__ Z, int nrows) {
    __shared__ float sW[64 * 64];
    __shared__ float sX[64][64];
    int tid = threadIdx.x;
    int c = tid & 63;
    int rg = tid >> 6;          // 0..3 (wave id)
    for (int i = tid; i < 64 * 64; i += 256) sW[i] = W[i];
    int base = blockIdx.x * 64;
    for (int r = rg; r < 64; r += 4) {
        int row = base + r;
        sX[r][c] = (row < nrows) ? (float)X[(size_t)row * 64 + c] : 0.f;
    }
    __syncthreads();
#pragma unroll
    for (int t = 0; t < 16; ++t) {
        int r = t * 4 + rg;
        float acc = 0.f;
#pragma unroll
        for (int k = 0; k < 64; ++k) acc += sX[r][k] * sW[k * 64 + c];
        int row = base + r;
        if (row < nrows) Z[(size_t)row * 64 + c] = __float2half(acc);
    }
}

// ---- CSR build ----
// coarse histogram: edges per 256-node bucket
__global__ void coarse_hist(const int* __restrict__ dst, int* __restrict__ bcnt, int E) {
    __shared__ int h[256];
    int t = threadIdx.x;
    h[t] = 0;
    __syncthreads();
    for (int i = blockIdx.x * blockDim.x + t; i < E; i += gridDim.x * blockDim.x)
        atomicAdd(&h[dst[i] >> 8], 1);
    __syncthreads();
    if (h[t] > 0) atomicAdd(&bcnt[t], h[t]);
}

// scan bucket counts -> bucket offsets + pass-A cursors; rowptr[N]=E
__global__ void bucket_offsets(const int* __restrict__ bcnt, int* __restrict__ boff,
                               int* __restrict__ ccur, int nb, int E,
                               int* __restrict__ rowptr, int N) {
    __shared__ int s[256];
    int t = threadIdx.x;
    int v = (t < nb) ? bcnt[t] : 0;
    s[t] = v;
    __syncthreads();
    for (int off = 1; off < 256; off <<= 1) {
        int u = (t >= off) ? s[t - off] : 0;
        __syncthreads();
        s[t] += u;
        __syncthreads();
    }
    int excl = s[t] - v;
    if (t < nb) { boff[t] = excl; ccur[t] = excl; }
    if (t == 0) { boff[nb] = E; rowptr[N] = E; }
}

// pass A: coarse-bucket (src,dst) into staging, LDS-staged chunks
__global__ void bucket_scatter(const int* __restrict__ src, const int* __restrict__ dst,
                               int* __restrict__ ccur, int2* __restrict__ staging, int E) {
    __shared__ int esrc[CHUNK];
    __shared__ int edst[CHUNK];
    __shared__ int hist[256];
    __shared__ int base[256];
    int t = threadIdx.x;
    int begin = blockIdx.x * CHUNK;
    int cnt = min(CHUNK, E - begin);
    hist[t] = 0;
    __syncthreads();
    for (int i = t; i < cnt; i += 256) {
        int d = dst[begin + i];
        esrc[i] = src[begin + i];
        edst[i] = d;
        atomicAdd(&hist[d >> 8], 1);
    }
    __syncthreads();
    int h = hist[t];
    if (h > 0) base[t] = atomicAdd(&ccur[t], h);
    hist[t] = 0;
    __syncthreads();
    for (int i = t; i < cnt; i += 256) {
        int d = edst[i];
        int b = d >> 8;
        int p = base[b] + atomicAdd(&hist[b], 1);
        staging[p] = make_int2(esrc[i], d);
    }
}

// pass B: one block per bucket; per-node hist+scan+scatter fully in LDS
__global__ void bucket_finalize(const int2* __restrict__ staging, const int* __restrict__ boff,
                                int* __restrict__ rowptr, int* __restrict__ col, int N) {
    __shared__ int2 edges[CAP];
    __shared__ int hist[256];
    __shared__ int scan[256];
    __shared__ int cur[256];
    int b = blockIdx.x, t = threadIdx.x;
    int lo = boff[b], hi = boff[b + 1];
    int cnt = hi - lo;
    hist[t] = 0;
    __syncthreads();
    for (int i = t; i < cnt; i += 256) {
        int2 e = staging[lo + i];
        if (i < CAP) edges[i] = e;
        atomicAdd(&hist[e.y & 255], 1);
    }
    __syncthreads();
    int v = hist[t];
    scan[t] = v;
    __syncthreads();
    for (int off = 1; off < 256; off <<= 1) {
        int u = (t >= off) ? scan[t - off] : 0;
        __syncthreads();
        scan[t] += u;
        __syncthreads();
    }
    int excl = scan[t] - v;
    cur[t] = excl;
    int node = b * 256 + t;
    if (node < N) rowptr[node] = lo + excl;
    __syncthreads();
    for (int i = t; i < cnt; i += 256) {
        int2 e = (i < CAP) ? edges[i] : staging[lo + i];
        int pos = lo + atomicAdd(&cur[e.y & 255], 1);
        col[pos] = e.x;
    }
}

// ---- gather + bias + relu; 1 wave/node; 16 rows in flight ----
__global__ void gather_relu(const __half* __restrict__ Z, const int* __restrict__ rowptr,
                            const int* __restrict__ col, const float* __restrict__ bias,
                            __half* __restrict__ H, int n) {
    int node = (int)((blockIdx.x * blockDim.x + threadIdx.x) >> 6);
    if (node >= n) return;
    int lane = threadIdx.x & 63;
    int g = lane >> 4, l = lane & 15;
    int lo = rowptr[node], hi = rowptr[node + 1];
    const float2* Z2 = reinterpret_cast<const float2*>(Z);
    float ax = 0.f, ay = 0.f, az = 0.f, aw = 0.f;
    int j = lo + g;
    while (j + 12 < hi) {
        int s0 = col[j], s1 = col[j + 4], s2 = col[j + 8], s3 = col[j + 12];
        float2 r0 = Z2[(size_t)s0 * 16 + l];
        float2 r1 = Z2[(size_t)s1 * 16 + l];
        float2 r2 = Z2[(size_t)s2 * 16 + l];
        float2 r3 = Z2[(size_t)s3 * 16 + l];
        float2 f;
        f = __half22float2(*(__half2*)&r0.x); ax += f.x; ay += f.y;
        f = __half22float2(*(__half2*)&r0.y); az += f.x; aw += f.y;
        f = __half22float2(*(__half2*)&r1.x); ax += f.x; ay += f.y;
        f = __half22float2(*(__half2*)&r1.y); az += f.x; aw += f.y;
        f = __half22float2(*(__half2*)&r2.x); ax += f.x; ay += f.y;
        f = __half22float2(*(__half2*)&r2.y); az += f.x; aw += f.y;
        f = __half22float2(*(__half2*)&r3.x); ax += f.x; ay += f.y;
        f = __half22float2(*(__half2*)&r3.y); az += f.x; aw += f.y;
        j += 16;
    }
    for (; j < hi; j += 4) {
        float2 r = Z2[(size_t)col[j] * 16 + l];
        float2 f0 = __half22float2(*(__half2*)&r.x);
        float2 f1 = __half22float2(*(__half2*)&r.y);
        ax += f0.x; ay += f0.y; az += f1.x; aw += f1.y;
    }
    ax += __shfl_xor(ax, 16); ay += __shfl_xor(ay, 16);
    az += __shfl_xor(az, 16); aw += __shfl_xor(aw, 16);
    ax += __shfl_xor(ax, 32); ay += __shfl_xor(ay, 32);
    az += __shfl_xor(az, 32); aw += __shfl_xor(aw, 32);
    if (g == 0) {
        float2 sr = Z2[(size_t)node * 16 + l];
        float2 fs0 = __half22float2(*(__half2*)&sr.x);
        float2 fs1 = __half22float2(*(__half2*)&sr.y);
        float4 b = reinterpret_cast<const float4*>(bias)[l];
        __half2 o0 = __floats2half2_rn(fmaxf(fs0.x + ax + b.x, 0.f),
                                       fmaxf(fs0.y + ay + b.y, 0.f));
        __half2 o1 = __floats2half2_rn(fmaxf(fs1.x + az + b.z, 0.f),
                                       fmaxf(fs1.y + aw + b.w, 0.f));
        float2 outv;
        *(__half2*)&outv.x = o0;
        *(__half2*)&outv.y = o1;
        reinterpret_cast<float2*>(H)[(size_t)node * 16 + l] = outv;
    }
}

// ---- fused mean-pool + linear head; 256 threads/graph ----
__global__ void pool_head(const __half* __restrict__ H, const int* __restrict__ batch,
                          const float* __restrict__ W3, const float* __restrict__ b3,
                          float* __restrict__ out, int n, int ncls) {
    int gidx = blockIdx.x;
    __shared__ int bounds[2];
    __shared__ float sred[4 * 64];
    __shared__ float row[64];
    int t = threadIdx.x;                 // 0..255
    int w = t >> 6;
    int lane = t & 63;
    int g = lane >> 4, l = lane & 15;
    if (t < 2) {
        int target = gidx + t;
        int lo = 0, hi = n;
        while (lo < hi) { int m = (lo + hi) >> 1; if (batch[m] < target) lo = m + 1; else hi = m; }
        bounds[t] = lo;
    }
    __syncthreads();
    int lo = bounds[0], hi = bounds[1];
    const float2* H2 = reinterpret_cast<const float2*>(H);
    float ax = 0.f, ay = 0.f, az = 0.f, aw = 0.f;
    for (int i = lo + (w * 4 + g); i < hi; i += 16) {
        float2 raw = H2[(size_t)i * 16 + l];
        float2 f0 = __half22float2(*(__half2*)&raw.x);
        float2 f1 = __half22float2(*(__half2*)&raw.y);
        ax += f0.x; ay += f0.y; az += f1.x; aw += f1.y;
    }
    ax += __shfl_xor(ax, 16); ay += __shfl_xor(ay, 16);
    az += __shfl_xor(az, 16); aw += __shfl_xor(aw, 16);
    ax += __shfl_xor(ax, 32); ay += __shfl_xor(ay, 32);
    az += __shfl_xor(az, 32); aw += __shfl_xor(aw, 32);
    if (g == 0) {
        sred[w * 64 + l * 4 + 0] = ax;
        sred[w * 64 + l * 4 + 1] = ay;
        sred[w * 64 + l * 4 + 2] = az;
        sred[w * 64 + l * 4 + 3] = aw;
    }
    __syncthreads();
    if (w == 0) {
        float s = sred[lane] + sred[64 + lane] + sred[128 + lane] + sred[192 + lane];
        row[lane] = s / fmaxf((float)(hi - lo), 1.0f);
    }
    __syncthreads();
    if (t < ncls) {
        float o = b3[t];
#pragma unroll
        for (int k = 0; k < 64; ++k) o += row[k] * W3[k * ncls + t];
        out[gidx * ncls + t] = o;
    }
}

extern "C" void kernel_launch(void* const* d_in, const int* in_sizes, int n_in,
                              void* d_out, int out_size, void* d_ws, size_t ws_size,
                              hipStream_t stream) {
    const float* x     = (const float*)d_in[0];
    const int*   ei    = (const int*)d_in[1];   // [2, E]
    const int*   batch = (const int*)d_in[2];
    const float* W1    = (const float*)d_in[3];
    const float* b1    = (const float*)d_in[4];
    const float* W2    = (const float*)d_in[5];
    const float* b2    = (const float*)d_in[6];
    const float* W3    = (const float*)d_in[7];
    const float* b3    = (const float*)d_in[8];
    float* out = (float*)d_out;

    const int N = in_sizes[0] / N_FEAT;       // 50000
    const int E = in_sizes[1] / 2;            // 800000
    const int NCLS = 10;
    const int G = out_size / NCLS;            // 500
    const int* src = ei;
    const int* dst = ei + E;

    // workspace layout
    int2*   staging = (int2*)d_ws;                        // E pairs
    __half* zbuf    = (__half*)(staging + E);             // N*64 fp16
    __half* hbuf    = zbuf + (size_t)N * 64;              // N*64 fp16
    int*    rowptr  = (int*)(hbuf + (size_t)N * 64);      // N+1
    int*    bcnt    = rowptr + (N + 1);                   // 256
    int*    boff    = bcnt + 256;                         // 257
    int*    ccur    = boff + 257;                         // 256
    int*    col     = ccur + 256;                         // E

    const int gemmGrid = (N + 63) / 64;
    const int gatherGrid = (N + 3) / 4;
    const int nb = (N + 255) / 256;           // 196 buckets
    const int scatGrid = (E + CHUNK - 1) / CHUNK;

    // ---- build CSR ----
    hipMemsetAsync(bcnt, 0, 256 * sizeof(int), stream);
    coarse_hist<<<400, 256, 0, stream>>>(dst, bcnt, E);
    bucket_offsets<<<1, 256, 0, stream>>>(bcnt, boff, ccur, nb, E, rowptr, N);
    bucket_scatter<<<scatGrid, 256, 0, stream>>>(src, dst, ccur, staging, E);
    bucket_finalize<<<nb, 256, 0, stream>>>(staging, boff, rowptr, col, N);

    // ---- layer 1 ----
    gemm64<float><<<gemmGrid, 256, 0, stream>>>(x, W1, zbuf, N);
    gather_relu<<<gatherGrid, 256, 0, stream>>>(zbuf, rowptr, col, b1, hbuf, N);

    // ---- layer 2 ----
    gemm64<__half><<<gemmGrid, 256, 0, stream>>>(hbuf, W2, zbuf, N);
    gather_relu<<<gatherGrid, 256, 0, stream>>>(zbuf, rowptr, col, b2, hbuf, N);

    // ---- pool + head ----
    pool_head<<<G, 256, 0, stream>>>(hbuf, batch, W3, b3, out, N, NCLS);
}

// Round 7
// 190.828 us; speedup vs baseline: 4.2336x; 1.3622x over previous
//
#include <hip/hip_runtime.h>
#include <hip/hip_bf16.h>
#include <hip/hip_fp16.h>

// GIN via linearity: agg(x)@W == agg(x@W). Per layer: z = X@W (MFMA fp16,
// fp32 accum), then h = relu(z + gather_sum(z) + b) via on-device CSR.
// CSR: single-pass fixed-capacity coarse buckets (dst>>8, CAP slots each) +
// LDS-local per-bucket finalize. No global scan, no float atomics.

#define N_FEAT 64
#define CHUNK 2048
#define CAP 6144   // slots per coarse bucket (mean fill 4096, >30 sigma slack)

typedef _Float16 f16;
typedef _Float16 half8 __attribute__((ext_vector_type(8)));
typedef float float4v __attribute__((ext_vector_type(4)));

__device__ inline f16 cvt_f16(float v) { return (f16)v; }
__device__ inline f16 cvt_f16(f16 v) { return v; }

// ---- GEMM via MFMA: 64 rows/block, 4 waves; wave w = 16-row strip ----
// sX[r][k], sWT[n][k] fp16 in LDS (stride 72 halves -> 2-way bank alias, free).
// A[m=lane&15][k=quad*8+j], B[n=lane&15][k=quad*8+j], D row=quad*4+reg,col=lane&15.
template <typename TIN>
__global__ void gemm_mfma(const TIN* __restrict__ X, const float* __restrict__ W,
                          f16* __restrict__ Z, int nrows) {
    __shared__ f16 sX[64][72];
    __shared__ f16 sWT[64][72];
    int t = threadIdx.x;
    int base = blockIdx.x * 64;
    for (int idx = t; idx < 4096; idx += 256) {
        int k = idx >> 6, n = idx & 63;
        sWT[n][k] = (f16)W[idx];               // W[k][n] -> sWT[n][k]
    }
    for (int idx = t; idx < 4096; idx += 256) {
        int r = idx >> 6, c = idx & 63;
        int row = base + r;
        sX[r][c] = (row < nrows) ? cvt_f16(X[(size_t)row * 64 + c]) : (f16)0.f;
    }
    __syncthreads();
    int wave = t >> 6;
    int lane = t & 63;
    int quad = lane >> 4;
    int m16 = lane & 15;
    half8 a0 = *(const half8*)&sX[wave * 16 + m16][quad * 8];
    half8 a1 = *(const half8*)&sX[wave * 16 + m16][32 + quad * 8];
    float4v acc[4];
#pragma unroll
    for (int C = 0; C < 4; ++C) {
        half8 b0 = *(const half8*)&sWT[C * 16 + m16][quad * 8];
        half8 b1 = *(const half8*)&sWT[C * 16 + m16][32 + quad * 8];
        float4v d = {0.f, 0.f, 0.f, 0.f};
        d = __builtin_amdgcn_mfma_f32_16x16x32_f16(a0, b0, d, 0, 0, 0);
        d = __builtin_amdgcn_mfma_f32_16x16x32_f16(a1, b1, d, 0, 0, 0);
        acc[C] = d;
    }
#pragma unroll
    for (int reg = 0; reg < 4; ++reg) {
        int row = base + wave * 16 + quad * 4 + reg;
        if (row < nrows) {
#pragma unroll
            for (int C = 0; C < 4; ++C)
                Z[(size_t)row * 64 + C * 16 + m16] = (f16)acc[C][reg];
        }
    }
}

// ---- CSR pass A: coarse-bucket (src,dst) into fixed-capacity regions ----
__global__ void bucket_scatter(const int* __restrict__ src, const int* __restrict__ dst,
                               int* __restrict__ ccur, int2* __restrict__ staging, int E) {
    __shared__ int esrc[CHUNK];
    __shared__ int edst[CHUNK];
    __shared__ int hist[256];
    __shared__ int base[256];
    int t = threadIdx.x;
    int begin = blockIdx.x * CHUNK;
    int cnt = min(CHUNK, E - begin);
    hist[t] = 0;
    __syncthreads();
    for (int i = t; i < cnt; i += 256) {
        int d = dst[begin + i];
        esrc[i] = src[begin + i];
        edst[i] = d;
        atomicAdd(&hist[d >> 8], 1);
    }
    __syncthreads();
    int h = hist[t];
    if (h > 0) base[t] = atomicAdd(&ccur[t], h);
    hist[t] = 0;
    __syncthreads();
    for (int i = t; i < cnt; i += 256) {
        int d = edst[i];
        int b = d >> 8;
        int off = base[b] + atomicAdd(&hist[b], 1);
        if (off < CAP) staging[(size_t)b * CAP + off] = make_int2(esrc[i], d);
    }
}

// ---- CSR pass B: per-bucket hist+scan+scatter fully in LDS ----
__global__ void bucket_finalize(const int2* __restrict__ staging, const int* __restrict__ ccur,
                                int2* __restrict__ rowse, int* __restrict__ col, int N) {
    __shared__ int2 edges[CAP];
    __shared__ int hist[256];
    __shared__ int scan[256];
    __shared__ int cur[256];
    int b = blockIdx.x, t = threadIdx.x;
    int cnt = min(ccur[b], CAP);
    int sbase = b * CAP;
    hist[t] = 0;
    __syncthreads();
    for (int i = t; i < cnt; i += 256) {
        int2 e = staging[(size_t)sbase + i];
        edges[i] = e;
        atomicAdd(&hist[e.y & 255], 1);
    }
    __syncthreads();
    int v = hist[t];
    scan[t] = v;
    __syncthreads();
    for (int off = 1; off < 256; off <<= 1) {
        int u = (t >= off) ? scan[t - off] : 0;
        __syncthreads();
        scan[t] += u;
        __syncthreads();
    }
    int excl = scan[t] - v;
    cur[t] = excl;
    int node = b * 256 + t;
    if (node < N) rowse[node] = make_int2(sbase + excl, sbase + excl + v);
    __syncthreads();
    for (int i = t; i < cnt; i += 256) {
        int2 e = edges[i];
        int pos = sbase + atomicAdd(&cur[e.y & 255], 1);
        col[pos] = e.x;
    }
}

// ---- gather + bias + relu; 1 wave/node; 16 rows in flight ----
__global__ void gather_relu(const f16* __restrict__ Z, const int2* __restrict__ rowse,
                            const int* __restrict__ col, const float* __restrict__ bias,
                            f16* __restrict__ H, int n) {
    int node = (int)((blockIdx.x * blockDim.x + threadIdx.x) >> 6);
    if (node >= n) return;
    int lane = threadIdx.x & 63;
    int g = lane >> 4, l = lane & 15;
    int2 se = rowse[node];
    int lo = se.x, hi = se.y;
    const float2* Z2 = reinterpret_cast<const float2*>(Z);
    float ax = 0.f, ay = 0.f, az = 0.f, aw = 0.f;
    int j = lo + g;
    while (j + 12 < hi) {
        int s0 = col[j], s1 = col[j + 4], s2 = col[j + 8], s3 = col[j + 12];
        float2 r0 = Z2[(size_t)s0 * 16 + l];
        float2 r1 = Z2[(size_t)s1 * 16 + l];
        float2 r2 = Z2[(size_t)s2 * 16 + l];
        float2 r3 = Z2[(size_t)s3 * 16 + l];
        float2 f;
        f = __half22float2(*(__half2*)&r0.x); ax += f.x; ay += f.y;
        f = __half22float2(*(__half2*)&r0.y); az += f.x; aw += f.y;
        f = __half22float2(*(__half2*)&r1.x); ax += f.x; ay += f.y;
        f = __half22float2(*(__half2*)&r1.y); az += f.x; aw += f.y;
        f = __half22float2(*(__half2*)&r2.x); ax += f.x; ay += f.y;
        f = __half22float2(*(__half2*)&r2.y); az += f.x; aw += f.y;
        f = __half22float2(*(__half2*)&r3.x); ax += f.x; ay += f.y;
        f = __half22float2(*(__half2*)&r3.y); az += f.x; aw += f.y;
        j += 16;
    }
    for (; j < hi; j += 4) {
        float2 r = Z2[(size_t)col[j] * 16 + l];
        float2 f0 = __half22float2(*(__half2*)&r.x);
        float2 f1 = __half22float2(*(__half2*)&r.y);
        ax += f0.x; ay += f0.y; az += f1.x; aw += f1.y;
    }
    ax += __shfl_xor(ax, 16); ay += __shfl_xor(ay, 16);
    az += __shfl_xor(az, 16); aw += __shfl_xor(aw, 16);
    ax += __shfl_xor(ax, 32); ay += __shfl_xor(ay, 32);
    az += __shfl_xor(az, 32); aw += __shfl_xor(aw, 32);
    if (g == 0) {
        float2 sr = Z2[(size_t)node * 16 + l];
        float2 fs0 = __half22float2(*(__half2*)&sr.x);
        float2 fs1 = __half22float2(*(__half2*)&sr.y);
        float4 b = reinterpret_cast<const float4*>(bias)[l];
        __half2 o0 = __floats2half2_rn(fmaxf(fs0.x + ax + b.x, 0.f),
                                       fmaxf(fs0.y + ay + b.y, 0.f));
        __half2 o1 = __floats2half2_rn(fmaxf(fs1.x + az + b.z, 0.f),
                                       fmaxf(fs1.y + aw + b.w, 0.f));
        float2 outv;
        *(__half2*)&outv.x = o0;
        *(__half2*)&outv.y = o1;
        reinterpret_cast<float2*>(H)[(size_t)node * 16 + l] = outv;
    }
}

// ---- fused mean-pool + linear head; 256 threads/graph ----
__global__ void pool_head(const f16* __restrict__ H, const int* __restrict__ batch,
                          const float* __restrict__ W3, const float* __restrict__ b3,
                          float* __restrict__ out, int n, int ncls) {
    int gidx = blockIdx.x;
    __shared__ int bounds[2];
    __shared__ float sred[4 * 64];
    __shared__ float row[64];
    int t = threadIdx.x;                 // 0..255
    int w = t >> 6;
    int lane = t & 63;
    int g = lane >> 4, l = lane & 15;
    if (t < 2) {
        int target = gidx + t;
        int lo = 0, hi = n;
        while (lo < hi) { int m = (lo + hi) >> 1; if (batch[m] < target) lo = m + 1; else hi = m; }
        bounds[t] = lo;
    }
    __syncthreads();
    int lo = bounds[0], hi = bounds[1];
    const float2* H2 = reinterpret_cast<const float2*>(H);
    float ax = 0.f, ay = 0.f, az = 0.f, aw = 0.f;
    for (int i = lo + (w * 4 + g); i < hi; i += 16) {
        float2 raw = H2[(size_t)i * 16 + l];
        float2 f0 = __half22float2(*(__half2*)&raw.x);
        float2 f1 = __half22float2(*(__half2*)&raw.y);
        ax += f0.x; ay += f0.y; az += f1.x; aw += f1.y;
    }
    ax += __shfl_xor(ax, 16); ay += __shfl_xor(ay, 16);
    az += __shfl_xor(az, 16); aw += __shfl_xor(aw, 16);
    ax += __shfl_xor(ax, 32); ay += __shfl_xor(ay, 32);
    az += __shfl_xor(az, 32); aw += __shfl_xor(aw, 32);
    if (g == 0) {
        sred[w * 64 + l * 4 + 0] = ax;
        sred[w * 64 + l * 4 + 1] = ay;
        sred[w * 64 + l * 4 + 2] = az;
        sred[w * 64 + l * 4 + 3] = aw;
    }
    __syncthreads();
    if (w == 0) {
        float s = sred[lane] + sred[64 + lane] + sred[128 + lane] + sred[192 + lane];
        row[lane] = s / fmaxf((float)(hi - lo), 1.0f);
    }
    __syncthreads();
    if (t < ncls) {
        float o = b3[t];
#pragma unroll
        for (int k = 0; k < 64; ++k) o += row[k] * W3[k * ncls + t];
        out[gidx * ncls + t] = o;
    }
}

extern "C" void kernel_launch(void* const* d_in, const int* in_sizes, int n_in,
                              void* d_out, int out_size, void* d_ws, size_t ws_size,
                              hipStream_t stream) {
    const float* x     = (const float*)d_in[0];
    const int*   ei    = (const int*)d_in[1];   // [2, E]
    const int*   batch = (const int*)d_in[2];
    const float* W1    = (const float*)d_in[3];
    const float* b1    = (const float*)d_in[4];
    const float* W2    = (const float*)d_in[5];
    const float* b2    = (const float*)d_in[6];
    const float* W3    = (const float*)d_in[7];
    const float* b3    = (const float*)d_in[8];
    float* out = (float*)d_out;

    const int N = in_sizes[0] / N_FEAT;       // 50000
    const int E = in_sizes[1] / 2;            // 800000
    const int NCLS = 10;
    const int G = out_size / NCLS;            // 500
    const int* src = ei;
    const int* dst = ei + E;
    const int nb = (N + 255) / 256;           // 196 coarse buckets

    // workspace layout (ws ~268 MB; we use ~28 MB)
    int2* staging = (int2*)d_ws;                          // nb*CAP pairs
    int2* rowse   = staging + (size_t)nb * CAP;           // N
    int*  col     = (int*)(rowse + N);                    // nb*CAP
    int*  ccur    = col + (size_t)nb * CAP;               // 256
    f16*  zbuf    = (f16*)(ccur + 256);                   // N*64
    f16*  hbuf    = zbuf + (size_t)N * 64;                // N*64

    const int gemmGrid = (N + 63) / 64;
    const int gatherGrid = (N + 3) / 4;
    const int scatGrid = (E + CHUNK - 1) / CHUNK;

    // ---- build CSR ----
    hipMemsetAsync(ccur, 0, 256 * sizeof(int), stream);
    bucket_scatter<<<scatGrid, 256, 0, stream>>>(src, dst, ccur, staging, E);
    bucket_finalize<<<nb, 256, 0, stream>>>(staging, ccur, rowse, col, N);

    // ---- layer 1 ----
    gemm_mfma<float><<<gemmGrid, 256, 0, stream>>>(x, W1, zbuf, N);
    gather_relu<<<gatherGrid, 256, 0, stream>>>(zbuf, rowse, col, b1, hbuf, N);

    // ---- layer 2 ----
    gemm_mfma<f16><<<gemmGrid, 256, 0, stream>>>(hbuf, W2, zbuf, N);
    gather_relu<<<gatherGrid, 256, 0, stream>>>(zbuf, rowse, col, b2, hbuf, N);

    // ---- pool + head ----
    pool_head<<<G, 256, 0, stream>>>(hbuf, batch, W3, b3, out, N, NCLS);
}